// Round 3
// baseline (285.855 us; speedup 1.0000x reference)
//
#include <hip/hip_runtime.h>

#define Hh 160
#define Ww 160
#define HW 25600
#define Bb 8
#define Cc 64
#define Oo 64
#define NPIX (Bb * HW)   // 204800
#define WROW 72          // shorts per padded LDS weight row (144 B, 16B-aligned)

typedef __bf16 bf16x8 __attribute__((ext_vector_type(8)));
typedef float  f32x4  __attribute__((ext_vector_type(4)));
typedef float  f32x2  __attribute__((ext_vector_type(2)));

__device__ inline unsigned rnd_bf(float a) {
    unsigned u = __float_as_uint(a);
    return (u + 0x7FFFu + ((u >> 16) & 1u)) >> 16;   // RNE f32->bf16 (prep only)
}
__device__ inline unsigned pack_bf2(float a, float b) {
    unsigned ua = __float_as_uint(a) + 0x8000u;
    unsigned ub = __float_as_uint(b) + 0x8000u;
    return __builtin_amdgcn_perm(ub, ua, 0x07060302);
}
__device__ inline f32x2 up2(unsigned u) {
    f32x2 r;
    r.x = __uint_as_float(u << 16);
    r.y = __uint_as_float(u & 0xffff0000u);
    return r;
}
__device__ inline unsigned blend4(unsigned u00, unsigned u01, unsigned u10, unsigned u11,
                                  float w00, float w01, float w10, float w11) {
    f32x2 r = up2(u00) * w00 + up2(u01) * w01 + up2(u10) * w10 + up2(u11) * w11;
    return pack_bf2(r.x, r.y);
}
union UV { uint4 u; bf16x8 v; };
__device__ inline bf16x8 as_bf(uint4 u) { UV c; c.u = u; return c.v; }

// ---- prep: wtb[k][o 64][c] bf16 ; woffb[k][o pad32][c] bf16 ; BN fold ---------
__global__ __launch_bounds__(256) void prep_kernel(
    const float* __restrict__ w_dcn, const float* __restrict__ b_dcn,
    const float* __restrict__ w_off,
    const float* __restrict__ gamma, const float* __restrict__ beta,
    const float* __restrict__ run_mean, const float* __restrict__ run_var,
    unsigned short* __restrict__ wtb, unsigned short* __restrict__ woffb,
    float* __restrict__ scaleb)
{
    int i = blockIdx.x * 256 + threadIdx.x;
    if (i < 9 * Oo * Cc) {                 // wtb: [k][o][c]
        int k = i >> 12, rem = i & 4095;
        int o = rem >> 6, c = rem & 63;
        wtb[i] = (unsigned short)rnd_bf(w_dcn[(o * Cc + c) * 9 + k]);
    }
    if (i < 9 * 32 * Cc) {                 // woffb: [k][o pad32][c]
        int k = i >> 11, rem = i & 2047;
        int o = rem >> 6, c = rem & 63;
        float v = (o < 18) ? w_off[(o * Cc + c) * 9 + k] : 0.0f;
        woffb[i] = (unsigned short)rnd_bf(v);
    }
    if (i < Oo) {
        float inv = gamma[i] * rsqrtf(run_var[i] + 1e-5f);
        scaleb[i]      = inv;
        scaleb[Oo + i] = b_dcn[i] * inv + (beta[i] - run_mean[i] * inv);
    }
}

// ---- transpose x: NCHW fp32 -> NHWC bf16; XCD swizzle matches dcn_kernel ------
__global__ __launch_bounds__(256, 4) void xpose_kernel(
    const float* __restrict__ x, unsigned short* __restrict__ xhwc)
{
    __shared__ float tile[64 * 65];
    int blk = blockIdx.x;                  // 3200
    int nb  = (blk & 7) * 400 + (blk >> 3);
    int b = nb / 400, hw0 = (nb % 400) * 64;
    int t = threadIdx.x;
    int lane = t & 63, grp = t >> 6;

    const float* xp = x + (size_t)b * Cc * HW + hw0 + lane;
#pragma unroll
    for (int i = 0; i < 16; ++i) {
        int c = i * 4 + grp;
        tile[lane * 65 + c] = xp[(size_t)c * HW];
    }
    __syncthreads();

    int px  = t >> 2;                      // 0..63
    int ch0 = (t & 3) * 16;
    const float* row = tile + px * 65 + ch0;
    unsigned u[8];
#pragma unroll
    for (int j = 0; j < 8; ++j) u[j] = pack_bf2(row[2 * j], row[2 * j + 1]);
    unsigned short* dst = xhwc + ((size_t)(b * HW + hw0 + px)) * 64 + ch0;
    *(uint4*)dst       = make_uint4(u[0], u[1], u[2], u[3]);
    *(uint4*)(dst + 8) = make_uint4(u[4], u[5], u[6], u[7]);
}

// gather buffer: 8 raw uint4 (4 corners x lo/hi) + 4 bilinear weights.
struct GBuf { uint4 g[8]; float w[4]; };

// ---- fused: offset-conv(MFMA) + deform-sample + projection(MFMA) + BN + ReLU --
// v4: one image ROW per block (160 px, 640 thr, 10 waves). Grid = 1280 =
// exactly 5 blocks/CU, 160 rows/XCD -> zero tail imbalance. Barrier-locked
// tap-rounds per CU drop 225 -> 90 and weight-staging traffic 354 -> 142 MB
// vs the 64-px version; per-pixel gather work is unchanged (it is minimal).
// Staging is write-late (T14): load at tap top, ds_write after MATH — vmcnt
// in-order retire means the gathers' wait covers the older staging loads.
__global__ __launch_bounds__(640, 6) void dcn_kernel(
    const unsigned short* __restrict__ xhwc,
    const unsigned short* __restrict__ wtb,     // [9][64][64]
    const unsigned short* __restrict__ woffb,   // [9][32][64]
    const float* __restrict__ b_off,
    const float* __restrict__ scaleb,
    float* __restrict__ out)
{
    __shared__ __align__(16) short wdcn[2 * 64 * WROW];   // 18432 B
    __shared__ __align__(16) short woff[2 * 32 * WROW];   //  9216 B
    __shared__ __align__(16) float offb[160 * 20];        // 12800 B  (tot 40448)

    const int t = threadIdx.x;
    const int lane = t & 63, wv = t >> 6;      // wv in 0..9
    const int m = lane & 15, quad = lane >> 4;

    int blk = blockIdx.x;                      // 1280
    int b   = blk & 7;                         // XCD swizzle: 1 image/XCD
    int h   = blk >> 3;                        // 0..159
    int hw0 = h * Ww;
    int p   = wv * 16 + m;                     // this lane's pixel = its w coord
    int w   = p;

    const unsigned short* xq = xhwc + (size_t)b * HW * 64 + quad * 8;
    const uint4* wtb4  = (const uint4*)wtb;
    const uint4* wofb4 = (const uint4*)woffb;

    // ================= phase 1: offset conv (dbuf LDS weights) =================
    f32x4 oa0 = {0,0,0,0}, oa1 = {0,0,0,0};
    {   // stage tap 0 -> buf 0 (32 rows x 8 chunks = 256, threads 0..255)
        if (t < 256) {
            uint4 v = wofb4[t];
            *(uint4*)((char*)woff + (t >> 3) * (WROW * 2) + (t & 7) * 16) = v;
        }
    }
    __syncthreads();
#pragma unroll 1
    for (int k = 0; k < 9; ++k) {
        int cur = k & 1;
        uint4 wsv;
        if (k < 8 && t < 256) wsv = wofb4[(k + 1) * 256 + t];   // stage-load k+1
        {
            int hp = h + (k / 3) - 1, wp = w + (k % 3) - 1;
            bool ok = (hp >= 0) & (hp < Hh) & (wp >= 0) & (wp < Ww);
            int hps = min(max(hp, 0), Hh - 1), wps = min(max(wp, 0), Ww - 1);
            const unsigned short* src = xq + (size_t)(hps * Ww + wps) * 64;
            uint4 r0 = *(const uint4*)(src);
            uint4 r1 = *(const uint4*)(src + 32);
            if (!ok) { r0 = make_uint4(0,0,0,0); r1 = make_uint4(0,0,0,0); }
            bf16x8 a0 = as_bf(r0), a1 = as_bf(r1);

            const short* wb = woff + cur * 32 * WROW + quad * 8;
            bf16x8 b00 = *(const bf16x8*)(wb + m * WROW);
            bf16x8 b01 = *(const bf16x8*)(wb + m * WROW + 32);
            bf16x8 b10 = *(const bf16x8*)(wb + (m + 16) * WROW);
            bf16x8 b11 = *(const bf16x8*)(wb + (m + 16) * WROW + 32);
            oa0 = __builtin_amdgcn_mfma_f32_16x16x32_bf16(a0, b00, oa0, 0, 0, 0);
            oa0 = __builtin_amdgcn_mfma_f32_16x16x32_bf16(a1, b01, oa0, 0, 0, 0);
            oa1 = __builtin_amdgcn_mfma_f32_16x16x32_bf16(a0, b10, oa1, 0, 0, 0);
            oa1 = __builtin_amdgcn_mfma_f32_16x16x32_bf16(a1, b11, oa1, 0, 0, 0);
        }
        if (k < 8 && t < 256) {   // write-late staging
            *(uint4*)((char*)(woff + (cur ^ 1) * 32 * WROW)
                      + (t >> 3) * (WROW * 2) + (t & 7) * 16) = wsv;
        }
        __syncthreads();
    }

    // offsets -> LDS (wave-private rows; same-wave ds_write->ds_read ordering
    // handled by compiler lgkmcnt — no barrier needed)
    {
        float bo0 = b_off[m];
        float bo1 = (m < 2) ? b_off[16 + m] : 0.0f;
#pragma unroll
        for (int r = 0; r < 4; ++r) {
            int pp = wv * 16 + quad * 4 + r;
            offb[pp * 20 + m] = oa0[r] + bo0;
            if (m < 2) offb[pp * 20 + 16 + m] = oa1[r] + bo1;
        }
    }
    {   // stage dcn tap 0 -> buf 0 (64 rows x 8 chunks = 512, threads 0..511)
        if (t < 512) {
            uint4 v = wtb4[t];
            *(uint4*)((char*)wdcn + (t >> 3) * (WROW * 2) + (t & 7) * 16) = v;
        }
    }
    __syncthreads();

    // ================= phase 2: deform sample + projection =================
    f32x4 c0 = {0,0,0,0}, c1 = {0,0,0,0}, c2 = {0,0,0,0}, c3 = {0,0,0,0};
    const int p20 = p * 20;
#pragma unroll 1
    for (int k = 0; k < 9; ++k) {
        int cur = k & 1;
        uint4 sv;
        if (k < 8 && t < 512) sv = wtb4[(k + 1) * 512 + t];     // stage-load k+1

        float offy = offb[p20 + 2 * k];
        float offx = offb[p20 + 2 * k + 1];
        float py = (float)(h + k / 3 - 1) + offy;
        float px = (float)(w + k % 3 - 1) + offx;
        float y0f = floorf(py), x0f = floorf(px);
        float fy = py - y0f, fx = px - x0f;
        int y0 = (int)y0f, x0i = (int)x0f;
        int y1 = y0 + 1, x1 = x0i + 1;
        bool vy0 = (y0 >= 0) & (y0 < Hh), vy1 = (y1 >= 0) & (y1 < Hh);
        bool vx0 = (x0i >= 0) & (x0i < Ww), vx1 = (x1 >= 0) & (x1 < Ww);
        float w00 = (vy0 & vx0) ? (1.0f - fy) * (1.0f - fx) : 0.0f;
        float w01 = (vy0 & vx1) ? (1.0f - fy) * fx : 0.0f;
        float w10 = (vy1 & vx0) ? fy * (1.0f - fx) : 0.0f;
        float w11 = (vy1 & vx1) ? fy * fx : 0.0f;
        int cy0 = min(max(y0, 0), Hh - 1), cy1 = min(max(y1, 0), Hh - 1);
        int cx0 = min(max(x0i, 0), Ww - 1), cx1 = min(max(x1, 0), Ww - 1);

        const unsigned short* s00 = xq + (size_t)(cy0 * Ww + cx0) * 64;
        const unsigned short* s01 = xq + (size_t)(cy0 * Ww + cx1) * 64;
        const unsigned short* s10 = xq + (size_t)(cy1 * Ww + cx0) * 64;
        const unsigned short* s11 = xq + (size_t)(cy1 * Ww + cx1) * 64;
        uint4 a00 = *(const uint4*)(s00), b00 = *(const uint4*)(s00 + 32);
        uint4 a01 = *(const uint4*)(s01), b01 = *(const uint4*)(s01 + 32);
        uint4 a10 = *(const uint4*)(s10), b10 = *(const uint4*)(s10 + 32);
        uint4 a11 = *(const uint4*)(s11), b11 = *(const uint4*)(s11 + 32);

        uint4 o0, o1;
        o0.x = blend4(a00.x, a01.x, a10.x, a11.x, w00, w01, w10, w11);
        o0.y = blend4(a00.y, a01.y, a10.y, a11.y, w00, w01, w10, w11);
        o0.z = blend4(a00.z, a01.z, a10.z, a11.z, w00, w01, w10, w11);
        o0.w = blend4(a00.w, a01.w, a10.w, a11.w, w00, w01, w10, w11);
        o1.x = blend4(b00.x, b01.x, b10.x, b11.x, w00, w01, w10, w11);
        o1.y = blend4(b00.y, b01.y, b10.y, b11.y, w00, w01, w10, w11);
        o1.z = blend4(b00.z, b01.z, b10.z, b11.z, w00, w01, w10, w11);
        o1.w = blend4(b00.w, b01.w, b10.w, b11.w, w00, w01, w10, w11);
        bf16x8 A0 = as_bf(o0), A1 = as_bf(o1);

        const short* wq = wdcn + cur * 64 * WROW + quad * 8;
        bf16x8 B0, B1;
        B0 = *(const bf16x8*)(wq + m * WROW);
        B1 = *(const bf16x8*)(wq + m * WROW + 32);
        c0 = __builtin_amdgcn_mfma_f32_16x16x32_bf16(A0, B0, c0, 0, 0, 0);
        c0 = __builtin_amdgcn_mfma_f32_16x16x32_bf16(A1, B1, c0, 0, 0, 0);
        B0 = *(const bf16x8*)(wq + (m + 16) * WROW);
        B1 = *(const bf16x8*)(wq + (m + 16) * WROW + 32);
        c1 = __builtin_amdgcn_mfma_f32_16x16x32_bf16(A0, B0, c1, 0, 0, 0);
        c1 = __builtin_amdgcn_mfma_f32_16x16x32_bf16(A1, B1, c1, 0, 0, 0);
        B0 = *(const bf16x8*)(wq + (m + 32) * WROW);
        B1 = *(const bf16x8*)(wq + (m + 32) * WROW + 32);
        c2 = __builtin_amdgcn_mfma_f32_16x16x32_bf16(A0, B0, c2, 0, 0, 0);
        c2 = __builtin_amdgcn_mfma_f32_16x16x32_bf16(A1, B1, c2, 0, 0, 0);
        B0 = *(const bf16x8*)(wq + (m + 48) * WROW);
        B1 = *(const bf16x8*)(wq + (m + 48) * WROW + 32);
        c3 = __builtin_amdgcn_mfma_f32_16x16x32_bf16(A0, B0, c3, 0, 0, 0);
        c3 = __builtin_amdgcn_mfma_f32_16x16x32_bf16(A1, B1, c3, 0, 0, 0);

        if (k < 8 && t < 512) {   // write-late staging
            *(uint4*)((char*)(wdcn + (cur ^ 1) * 64 * WROW)
                      + (t >> 3) * (WROW * 2) + (t & 7) * 16) = sv;
        }
        __syncthreads();
    }

    // ---- epilogue: direct float4 stores (16 lines/instr, 64 B aligned) ----
#pragma unroll
    for (int nt = 0; nt < 4; ++nt) {
        f32x4 a = (nt == 0) ? c0 : (nt == 1) ? c1 : (nt == 2) ? c2 : c3;
        int o = nt * 16 + m;
        float sc = scaleb[o];
        float bs = scaleb[Oo + o];
        float4 r;
        r.x = fmaxf(a[0] * sc + bs, 0.0f);
        r.y = fmaxf(a[1] * sc + bs, 0.0f);
        r.z = fmaxf(a[2] * sc + bs, 0.0f);
        r.w = fmaxf(a[3] * sc + bs, 0.0f);
        float* op = out + ((size_t)b * Oo + o) * HW + hw0 + wv * 16 + quad * 4;
        *(float4*)op = r;
    }
}

extern "C" void kernel_launch(void* const* d_in, const int* in_sizes, int n_in,
                              void* d_out, int out_size, void* d_ws, size_t ws_size,
                              hipStream_t stream) {
    const float* x        = (const float*)d_in[0];
    const float* w_off    = (const float*)d_in[1];
    const float* b_off    = (const float*)d_in[2];
    const float* w_dcn    = (const float*)d_in[3];
    const float* b_dcn    = (const float*)d_in[4];
    const float* gamma    = (const float*)d_in[5];
    const float* beta     = (const float*)d_in[6];
    const float* run_mean = (const float*)d_in[7];
    const float* run_var  = (const float*)d_in[8];
    float* out = (float*)d_out;

    // workspace: xhwc (26.2 MB) | wtb | woffb | scaleb
    unsigned short* xhwc  = (unsigned short*)d_ws;
    unsigned short* wtb   = xhwc + (size_t)NPIX * 64;          // 9*64*64 bf16
    unsigned short* woffb = wtb + 9 * Oo * Cc;                 // 9*32*64 bf16
    float* scaleb         = (float*)(woffb + 9 * 32 * Cc);     // 128 floats

    prep_kernel<<<(9 * Oo * Cc + 255) / 256, 256, 0, stream>>>(
        w_dcn, b_dcn, w_off, gamma, beta, run_mean, run_var, wtb, woffb, scaleb);

    xpose_kernel<<<NPIX / 64, 256, 0, stream>>>(x, xhwc);

    dcn_kernel<<<NPIX / Ww, 640, 0, stream>>>(xhwc, wtb, woffb, b_off, scaleb, out);
}

// Round 4
// 206.347 us; speedup vs baseline: 1.3853x; 1.3853x over previous
//
#include <hip/hip_runtime.h>

#define Hh 160
#define Ww 160
#define HW 25600
#define Bb 8
#define Cc 64
#define Oo 64
#define NPIX (Bb * HW)   // 204800

#define TROWS 5
#define TCOLS 36
#define TPIX (TROWS * TCOLS)   // 180 pixel-rows in the LDS tile

typedef __bf16 bf16x8 __attribute__((ext_vector_type(8)));
typedef float  f32x4  __attribute__((ext_vector_type(4)));
typedef float  f32x2  __attribute__((ext_vector_type(2)));

__device__ inline unsigned rnd_bf(float a) {
    unsigned u = __float_as_uint(a);
    return (u + 0x7FFFu + ((u >> 16) & 1u)) >> 16;   // RNE f32->bf16 (prep only)
}
__device__ inline unsigned pack_bf2(float a, float b) {
    unsigned ua = __float_as_uint(a) + 0x8000u;
    unsigned ub = __float_as_uint(b) + 0x8000u;
    return __builtin_amdgcn_perm(ub, ua, 0x07060302);
}
__device__ inline f32x2 up2(unsigned u) {
    f32x2 r;
    r.x = __uint_as_float(u << 16);
    r.y = __uint_as_float(u & 0xffff0000u);
    return r;
}
__device__ inline unsigned blend4(unsigned u00, unsigned u01, unsigned u10, unsigned u11,
                                  float w00, float w01, float w10, float w11) {
    f32x2 r = up2(u00) * w00 + up2(u01) * w01 + up2(u10) * w10 + up2(u11) * w11;
    return pack_bf2(r.x, r.y);
}
union UV { uint4 u; bf16x8 v; };
__device__ inline bf16x8 as_bf(uint4 u) { UV c; c.u = u; return c.v; }

// ---- prep: fragment-major weights so dcn's B-loads are contiguous 1KB/wave ----
// wtbf[k][f][lane][8]: f in 0..7, o = (f>>1)*16 + (lane&15),
//                      c = (lane>>4)*8 + (f&1)*32 + j
// wofbf[k][f][lane][8]: f in 0..3, same formula, o>=18 zero-padded.
__global__ __launch_bounds__(256) void prep_kernel(
    const float* __restrict__ w_dcn, const float* __restrict__ b_dcn,
    const float* __restrict__ w_off,
    const float* __restrict__ gamma, const float* __restrict__ beta,
    const float* __restrict__ run_mean, const float* __restrict__ run_var,
    unsigned short* __restrict__ wtbf, unsigned short* __restrict__ wofbf,
    float* __restrict__ scaleb)
{
    int i = blockIdx.x * 256 + threadIdx.x;
    if (i < 9 * 8 * 64 * 8) {              // 36864
        int j = i & 7, l = (i >> 3) & 63, f = (i >> 9) & 7, k = i >> 12;
        int o  = ((f >> 1) << 4) | (l & 15);
        int cc = ((l >> 4) << 3) + ((f & 1) << 5) + j;
        wtbf[i] = (unsigned short)rnd_bf(w_dcn[(o * Cc + cc) * 9 + k]);
    }
    if (i < 9 * 4 * 64 * 8) {              // 18432
        int j = i & 7, l = (i >> 3) & 63, f = (i >> 9) & 3, k = i >> 11;
        int o  = ((f >> 1) << 4) | (l & 15);
        int cc = ((l >> 4) << 3) + ((f & 1) << 5) + j;
        float v = (o < 18) ? w_off[(o * Cc + cc) * 9 + k] : 0.0f;
        wofbf[i] = (unsigned short)rnd_bf(v);
    }
    if (i < Oo) {
        float inv = gamma[i] * rsqrtf(run_var[i] + 1e-5f);
        scaleb[i]      = inv;
        scaleb[Oo + i] = b_dcn[i] * inv + (beta[i] - run_mean[i] * inv);
    }
}

// ---- transpose x: NCHW fp32 -> NHWC bf16; XCD swizzle matches dcn_kernel ------
__global__ __launch_bounds__(256, 4) void xpose_kernel(
    const float* __restrict__ x, unsigned short* __restrict__ xhwc)
{
    __shared__ float tile[64 * 65];
    int blk = blockIdx.x;                  // 3200
    int nb  = (blk & 7) * 400 + (blk >> 3);
    int b = nb / 400, hw0 = (nb % 400) * 64;
    int t = threadIdx.x;
    int lane = t & 63, grp = t >> 6;

    const float* xp = x + (size_t)b * Cc * HW + hw0 + lane;
#pragma unroll
    for (int i = 0; i < 16; ++i) {
        int c = i * 4 + grp;
        tile[lane * 65 + c] = xp[(size_t)c * HW];
    }
    __syncthreads();

    int px  = t >> 2;                      // 0..63
    int ch0 = (t & 3) * 16;
    const float* row = tile + px * 65 + ch0;
    unsigned u[8];
#pragma unroll
    for (int j = 0; j < 8; ++j) u[j] = pack_bf2(row[2 * j], row[2 * j + 1]);
    unsigned short* dst = xhwc + ((size_t)(b * HW + hw0 + px)) * 64 + ch0;
    *(uint4*)dst       = make_uint4(u[0], u[1], u[2], u[3]);
    *(uint4*)(dst + 8) = make_uint4(u[4], u[5], u[6], u[7]);
}

// swizzled tile read: pixel-row PIX, this lane's two 16B chunks (quad, quad+4)
#define TRD(PIX, LO, HI) do {                                                  \
    int _pp = (PIX);                                                           \
    int _s  = _pp & 7;                                                         \
    const char* _tb = (const char*)tile + _pp * 128;                           \
    LO = *(const uint4*)(_tb + ((quad ^ _s) << 4));                            \
    HI = *(const uint4*)(_tb + (((quad + 4) ^ _s) << 4));                      \
} while (0)

// ---- fused: offset-conv(MFMA) + deform-sample + projection(MFMA) + BN + ReLU --
// v5: gathers from an LDS tile instead of scattered global loads.
// Block = 32 px of ONE row (128 thr, 2 waves). The 5-row x 36-col bf16
// neighborhood (23 KB) is staged ONCE, coalesced, XOR-swizzled; covers all
// corners whenever |offset| < 1 (sigma ~0.24). Rare out-of-window taps take a
// wave-uniform global-gather fallback (bit-identical result). Weights are
// fragment-major in global (coalesced, L1-hot) -> no weight LDS, no dbuf, and
// exactly ONE barrier in the kernel. Offsets live in registers for phase 2.
__global__ __launch_bounds__(128, 3) void dcn_kernel(
    const unsigned short* __restrict__ xhwc,
    const unsigned short* __restrict__ wtbf,    // [9][8][64][8]
    const unsigned short* __restrict__ wofbf,   // [9][4][64][8]
    const float* __restrict__ b_off,
    const float* __restrict__ scaleb,
    float* __restrict__ out)
{
    __shared__ __align__(16) unsigned short tile[TPIX * 64];  // 23040 B
    __shared__ __align__(16) float offb[32 * 20];             //  2560 B

    const int t = threadIdx.x;
    const int lane = t & 63, wv = t >> 6;      // wv 0..1
    const int m = lane & 15, quad = lane >> 4;

    int blk = blockIdx.x;                      // 6400
    int b   = blk & 7;                         // XCD swizzle: 1 image/XCD
    int nb  = blk >> 3;                        // 0..799
    int h   = nb / 5;                          // row
    int w0  = (nb % 5) * 32;                   // 32-px segment, row-aligned
    int p   = wv * 16 + m;                     // this lane's pixel
    int w   = w0 + p;

    const unsigned short* xb = xhwc + (size_t)b * HW * 64;
    const unsigned short* xq = xb + quad * 8;

    // ---- stage tile: rows h-2..h+2, cols w0-2..w0+33 (clamped), coalesced ----
    for (int id = t; id < TPIX * 8; id += 128) {
        int chunk = id & 7, pix = id >> 3;
        int r = pix / TCOLS, c = pix - r * TCOLS;
        int yr = min(max(h - 2 + r, 0), Hh - 1);
        int xc = min(max(w0 - 2 + c, 0), Ww - 1);
        uint4 v = *((const uint4*)(xb + ((size_t)yr * Ww + xc) * 64) + chunk);
        *(uint4*)((char*)tile + pix * 128 + ((chunk ^ (pix & 7)) << 4)) = v;
    }
    __syncthreads();   // the only barrier in this kernel

    // ================= phase 1: offset conv (A from tile, B global) ============
    f32x4 oa0 = {0,0,0,0}, oa1 = {0,0,0,0};
#pragma unroll
    for (int k = 0; k < 9; ++k) {
        int hp = h + k / 3 - 1, wp = w + (k % 3) - 1;
        bool ok = (hp >= 0) & (hp < Hh) & (wp >= 0) & (wp < Ww);
        int r = min(max(hp, 0), Hh - 1) - h + 2;       // in [0,4]
        int c = min(max(wp, 0), Ww - 1) - w0 + 2;      // in [0,35]
        uint4 r0, r1;
        TRD(r * TCOLS + c, r0, r1);
        if (!ok) { r0 = make_uint4(0,0,0,0); r1 = make_uint4(0,0,0,0); }
        bf16x8 a0 = as_bf(r0), a1 = as_bf(r1);

        const unsigned short* wf = wofbf + (size_t)(k * 4) * 512 + lane * 8;
        bf16x8 b00 = *(const bf16x8*)(wf);
        bf16x8 b01 = *(const bf16x8*)(wf + 512);
        bf16x8 b10 = *(const bf16x8*)(wf + 1024);
        bf16x8 b11 = *(const bf16x8*)(wf + 1536);
        oa0 = __builtin_amdgcn_mfma_f32_16x16x32_bf16(a0, b00, oa0, 0, 0, 0);
        oa0 = __builtin_amdgcn_mfma_f32_16x16x32_bf16(a1, b01, oa0, 0, 0, 0);
        oa1 = __builtin_amdgcn_mfma_f32_16x16x32_bf16(a0, b10, oa1, 0, 0, 0);
        oa1 = __builtin_amdgcn_mfma_f32_16x16x32_bf16(a1, b11, oa1, 0, 0, 0);
    }

    // offsets -> LDS transpose (wave-private rows) -> registers
    {
        float bo0 = b_off[m];
        float bo1 = (m < 2) ? b_off[16 + m] : 0.0f;
#pragma unroll
        for (int r = 0; r < 4; ++r) {
            int pp = wv * 16 + quad * 4 + r;
            offb[pp * 20 + m] = oa0[r] + bo0;
            if (m < 2) offb[pp * 20 + 16 + m] = oa1[r] + bo1;
        }
    }
    float oy[9], ox[9];
#pragma unroll
    for (int k = 0; k < 9; ++k) {
        f32x2 o = *(const f32x2*)&offb[p * 20 + 2 * k];
        oy[k] = o.x; ox[k] = o.y;
    }

    // ================= phase 2: deform sample (tile) + projection ==============
    f32x4 c0 = {0,0,0,0}, c1 = {0,0,0,0}, c2 = {0,0,0,0}, c3 = {0,0,0,0};
#pragma unroll
    for (int k = 0; k < 9; ++k) {
        float py = (float)(h + k / 3 - 1) + oy[k];
        float px = (float)(w + k % 3 - 1) + ox[k];
        float y0f = floorf(py), x0f = floorf(px);
        float fy = py - y0f, fx = px - x0f;
        int y0 = (int)y0f, x0i = (int)x0f;
        int y1 = y0 + 1, x1 = x0i + 1;
        bool vy0 = (y0 >= 0) & (y0 < Hh), vy1 = (y1 >= 0) & (y1 < Hh);
        bool vx0 = (x0i >= 0) & (x0i < Ww), vx1 = (x1 >= 0) & (x1 < Ww);
        float w00 = (vy0 & vx0) ? (1.0f - fy) * (1.0f - fx) : 0.0f;
        float w01 = (vy0 & vx1) ? (1.0f - fy) * fx : 0.0f;
        float w10 = (vy1 & vx0) ? fy * (1.0f - fx) : 0.0f;
        float w11 = (vy1 & vx1) ? fy * fx : 0.0f;
        int cy0 = min(max(y0, 0), Hh - 1), cy1 = min(max(y1, 0), Hh - 1);
        int cx0 = min(max(x0i, 0), Ww - 1), cx1 = min(max(x1, 0), Ww - 1);

        int r0 = cy0 - h + 2, r1 = cy1 - h + 2;        // tile coords
        int d0 = cx0 - w0 + 2, d1 = cx1 - w0 + 2;
        int inw = ((unsigned)r0 <= 4u) & ((unsigned)r1 <= 4u) &
                  ((unsigned)d0 <= 35u) & ((unsigned)d1 <= 35u);

        uint4 a00, h00, a01, h01, a10, h10, a11, h11;
        if (__all(inw)) {                              // fast path: LDS tile
            TRD(r0 * TCOLS + d0, a00, h00);
            TRD(r0 * TCOLS + d1, a01, h01);
            TRD(r1 * TCOLS + d0, a10, h10);
            TRD(r1 * TCOLS + d1, a11, h11);
        } else {                                       // rare: global gathers
            const unsigned short* s00 = xq + (size_t)(cy0 * Ww + cx0) * 64;
            const unsigned short* s01 = xq + (size_t)(cy0 * Ww + cx1) * 64;
            const unsigned short* s10 = xq + (size_t)(cy1 * Ww + cx0) * 64;
            const unsigned short* s11 = xq + (size_t)(cy1 * Ww + cx1) * 64;
            a00 = *(const uint4*)(s00); h00 = *(const uint4*)(s00 + 32);
            a01 = *(const uint4*)(s01); h01 = *(const uint4*)(s01 + 32);
            a10 = *(const uint4*)(s10); h10 = *(const uint4*)(s10 + 32);
            a11 = *(const uint4*)(s11); h11 = *(const uint4*)(s11 + 32);
        }

        uint4 o0, o1;
        o0.x = blend4(a00.x, a01.x, a10.x, a11.x, w00, w01, w10, w11);
        o0.y = blend4(a00.y, a01.y, a10.y, a11.y, w00, w01, w10, w11);
        o0.z = blend4(a00.z, a01.z, a10.z, a11.z, w00, w01, w10, w11);
        o0.w = blend4(a00.w, a01.w, a10.w, a11.w, w00, w01, w10, w11);
        o1.x = blend4(h00.x, h01.x, h10.x, h11.x, w00, w01, w10, w11);
        o1.y = blend4(h00.y, h01.y, h10.y, h11.y, w00, w01, w10, w11);
        o1.z = blend4(h00.z, h01.z, h10.z, h11.z, w00, w01, w10, w11);
        o1.w = blend4(h00.w, h01.w, h10.w, h11.w, w00, w01, w10, w11);
        bf16x8 A0 = as_bf(o0), A1 = as_bf(o1);

        const unsigned short* wf = wtbf + (size_t)(k * 8) * 512 + lane * 8;
        bf16x8 B0, B1;
        B0 = *(const bf16x8*)(wf);
        B1 = *(const bf16x8*)(wf + 512);
        c0 = __builtin_amdgcn_mfma_f32_16x16x32_bf16(A0, B0, c0, 0, 0, 0);
        c0 = __builtin_amdgcn_mfma_f32_16x16x32_bf16(A1, B1, c0, 0, 0, 0);
        B0 = *(const bf16x8*)(wf + 1024);
        B1 = *(const bf16x8*)(wf + 1536);
        c1 = __builtin_amdgcn_mfma_f32_16x16x32_bf16(A0, B0, c1, 0, 0, 0);
        c1 = __builtin_amdgcn_mfma_f32_16x16x32_bf16(A1, B1, c1, 0, 0, 0);
        B0 = *(const bf16x8*)(wf + 2048);
        B1 = *(const bf16x8*)(wf + 2560);
        c2 = __builtin_amdgcn_mfma_f32_16x16x32_bf16(A0, B0, c2, 0, 0, 0);
        c2 = __builtin_amdgcn_mfma_f32_16x16x32_bf16(A1, B1, c2, 0, 0, 0);
        B0 = *(const bf16x8*)(wf + 3072);
        B1 = *(const bf16x8*)(wf + 3584);
        c3 = __builtin_amdgcn_mfma_f32_16x16x32_bf16(A0, B0, c3, 0, 0, 0);
        c3 = __builtin_amdgcn_mfma_f32_16x16x32_bf16(A1, B1, c3, 0, 0, 0);
    }

    // ---- epilogue: BN + ReLU, direct float4 stores ----
#pragma unroll
    for (int nt = 0; nt < 4; ++nt) {
        f32x4 a = (nt == 0) ? c0 : (nt == 1) ? c1 : (nt == 2) ? c2 : c3;
        int o = nt * 16 + m;
        float sc = scaleb[o];
        float bs = scaleb[Oo + o];
        float4 r;
        r.x = fmaxf(a[0] * sc + bs, 0.0f);
        r.y = fmaxf(a[1] * sc + bs, 0.0f);
        r.z = fmaxf(a[2] * sc + bs, 0.0f);
        r.w = fmaxf(a[3] * sc + bs, 0.0f);
        float* op = out + ((size_t)b * Oo + o) * HW + h * Ww + w0 + wv * 16 + quad * 4;
        *(float4*)op = r;
    }
}

extern "C" void kernel_launch(void* const* d_in, const int* in_sizes, int n_in,
                              void* d_out, int out_size, void* d_ws, size_t ws_size,
                              hipStream_t stream) {
    const float* x        = (const float*)d_in[0];
    const float* w_off    = (const float*)d_in[1];
    const float* b_off    = (const float*)d_in[2];
    const float* w_dcn    = (const float*)d_in[3];
    const float* b_dcn    = (const float*)d_in[4];
    const float* gamma    = (const float*)d_in[5];
    const float* beta     = (const float*)d_in[6];
    const float* run_mean = (const float*)d_in[7];
    const float* run_var  = (const float*)d_in[8];
    float* out = (float*)d_out;

    // workspace: xhwc (26.2 MB) | wtbf | wofbf | scaleb
    unsigned short* xhwc  = (unsigned short*)d_ws;
    unsigned short* wtbf  = xhwc + (size_t)NPIX * 64;     // 9*8*64*8 bf16
    unsigned short* wofbf = wtbf + 9 * 8 * 64 * 8;        // 9*4*64*8 bf16
    float* scaleb         = (float*)(wofbf + 9 * 4 * 64 * 8);  // 128 floats

    prep_kernel<<<(9 * 8 * 64 * 8 + 255) / 256, 256, 0, stream>>>(
        w_dcn, b_dcn, w_off, gamma, beta, run_mean, run_var, wtbf, wofbf, scaleb);

    xpose_kernel<<<NPIX / 64, 256, 0, stream>>>(x, xhwc);

    dcn_kernel<<<NPIX / 32, 128, 0, stream>>>(xhwc, wtbf, wofbf, b_off, scaleb, out);
}